// Round 10
// baseline (461.668 us; speedup 1.0000x reference)
//
#include <hip/hip_runtime.h>
#include <stdint.h>

// Problem constants (static shapes from the reference)
constexpr int Bq = 2;
constexpr int Qn = 300;
constexpr int Cn = 80;
constexpr int Kn = 300;
constexpr int NFLAT = Qn * Cn;   // 24000
constexpr int MHs = 128;
constexpr int MWs = 128;
constexpr int THs = 320;
constexpr int TWs = 320;

// Output layout (flat concatenation in reference return order, all as float)
constexpr int OFF_SCORES = 0;                         // [B,K]     600
constexpr int OFF_LABELS = Bq * Kn;                   // [B,K]     600
constexpr int OFF_BOXES  = 2 * Bq * Kn;               // [B,K,4]   2400
constexpr int OFF_MASKS  = 2 * Bq * Kn + Bq * Kn * 4; // [B,K,320,320]

typedef float vf4  __attribute__((ext_vector_type(4)));              // 16B-aligned
typedef float uvf4 __attribute__((ext_vector_type(4), aligned(4)));  // align-4 load

// Workspace layout (bytes)
constexpr size_t WS_GHIST = 0;        // int[2*256]
constexpr size_t WS_CNT   = 2048;     // int[2]
constexpr size_t WS_THR   = 2064;     // int[2]
constexpr size_t WS_ZERO_BYTES = 2072;
constexpr size_t WS_CAND  = 4096;     // u64[2*1024]
constexpr size_t WS_QIDX  = 20480;    // int[600]

// ---------------------------------------------------------------------------
// MEASUREMENT ROUND: topk chain byte-identical to round 9; resize_sweep is
// launched 3x (idempotent). Round-9 total = OH + T + R = 345us; this round's
// total = OH + T + 3R, so dtotal = 2R gives the first direct measurement of
// the resize/topk split (everything below the ~165us poison fill is invisible
// to the top-5 rocprof table, and rounds 6-9 prove guessed attribution wrong).
// ---------------------------------------------------------------------------

__global__ __launch_bounds__(256) void tk_hist(
    const float* __restrict__ logits, int* __restrict__ ghist)
{
    const int b = blockIdx.y;
    __shared__ int lh[256];
    lh[threadIdx.x] = 0;
    __syncthreads();
    const float* lg = logits + (size_t)b * NFLAT;
    #pragma unroll
    for (int j = 0; j < 2; ++j) {
        int idx = blockIdx.x * 512 + j * 256 + threadIdx.x;
        if (idx < NFLAT) {
            float x = lg[idx];
            int bin = min(max((int)floorf((x + 8.0f) * 16.0f), 0), 255);
            atomicAdd(&lh[bin], 1);
        }
    }
    __syncthreads();
    int v = lh[threadIdx.x];
    if (v) atomicAdd(&ghist[b * 256 + threadIdx.x], v);
}

__global__ __launch_bounds__(64) void tk_thresh(
    const int* __restrict__ ghist, int* __restrict__ thr)
{
    const int b = blockIdx.x;
    if (threadIdx.x == 0) {
        int cum = 0, t = 0;
        for (int d = 255; d >= 0; --d) {
            cum += ghist[b * 256 + d];
            if (cum >= Kn) { t = d; break; }
        }
        thr[b] = t;
    }
}

__global__ __launch_bounds__(256) void tk_collect(
    const float* __restrict__ logits, const int* __restrict__ thr,
    int* __restrict__ cnt, unsigned long long* __restrict__ cand)
{
    const int b = blockIdx.y;
    const int T = thr[b];
    __shared__ unsigned long long lbuf[512];
    __shared__ int lcnt, lbase;
    if (threadIdx.x == 0) lcnt = 0;
    __syncthreads();
    const float* lg = logits + (size_t)b * NFLAT;
    #pragma unroll
    for (int j = 0; j < 2; ++j) {
        int idx = blockIdx.x * 512 + j * 256 + threadIdx.x;
        if (idx < NFLAT) {
            float x = lg[idx];
            int bin = min(max((int)floorf((x + 8.0f) * 16.0f), 0), 255);
            if (bin >= T) {
                float s = 1.0f / (1.0f + expf(-x));   // same formula rounds 1-9
                int p = atomicAdd(&lcnt, 1);
                if (p < 512)
                    lbuf[p] = ((unsigned long long)__float_as_uint(s) << 32)
                            | (unsigned long long)(0xFFFFFFFFu - (uint32_t)idx);
            }
        }
    }
    __syncthreads();
    if (threadIdx.x == 0) lcnt = min(lcnt, 512), lbase = atomicAdd(&cnt[b], lcnt);
    __syncthreads();
    for (int i = threadIdx.x; i < lcnt; i += 256) {
        int d = lbase + i;
        if (d < 1024) cand[b * 1024 + d] = lbuf[i];
    }
}

__global__ __launch_bounds__(1024) void tk_rank(
    const int* __restrict__ cnt, const unsigned long long* __restrict__ cand,
    const float* __restrict__ boxes, const float* __restrict__ osz,
    float* __restrict__ out, int* __restrict__ qidx_ws)
{
    const int b   = blockIdx.x;
    const int tid = threadIdx.x;
    __shared__ unsigned long long sk[1024];
    const int n = min(cnt[b], 1024);
    sk[tid] = (tid < n) ? cand[b * 1024 + tid] : 0ull;
    __syncthreads();

    if (tid < n) {
        unsigned long long my = sk[tid];
        int rank = 0;
        for (int i = 0; i < n; ++i) rank += (sk[i] > my) ? 1 : 0;
        if (rank < Kn) {
            uint32_t idx = 0xFFFFFFFFu - (uint32_t)(my & 0xFFFFFFFFull);
            float score  = __uint_as_float((uint32_t)(my >> 32));
            int label = (int)(idx % (uint32_t)Cn);
            int q     = (int)(idx / (uint32_t)Cn);

            out[OFF_SCORES + b * Kn + rank] = score;
            out[OFF_LABELS + b * Kn + rank] = (float)label;

            const float sw = osz[b * 2 + 0];
            const float sh = osz[b * 2 + 1];
            const float* bx = boxes + ((size_t)(b * Qn + q)) * 4;
            float cx = bx[0], cy = bx[1], w = bx[2], h = bx[3];
            float* ob = out + OFF_BOXES + ((size_t)(b * Kn + rank)) * 4;
            ob[0] = (cx - 0.5f * w) * sw;
            ob[1] = (cy - 0.5f * h) * sh;
            ob[2] = (cx + 0.5f * w) * sw;
            ob[3] = (cy + 0.5f * h) * sh;

            qidx_ws[b * Kn + rank] = q;
        }
    }
}

// ---------------------------------------------------------------------------
// resize v8 (byte-identical to round 9): grid-stride flat sweep.
// ---------------------------------------------------------------------------
constexpr int RS_GRID = 2400;
constexpr int RS_BLK  = 256;
constexpr int RS_THREADS = RS_GRID * RS_BLK;               // 614400
constexpr int N4 = Bq * Kn * (THs * TWs / 4);              // 15,360,000
constexpr int RS_ITERS = N4 / RS_THREADS;                  // 25 (exact)

__global__ __launch_bounds__(256) void resize_sweep(
    const float* __restrict__ masks,    // [B,Q,128,128]
    const int* __restrict__ qidx_ws,    // [B,K]
    float* __restrict__ out)
{
    __shared__ int  qlds[Bq * Kn];
    __shared__ int  s0lds[80];
    __shared__ vf4  Wlds[4 * 80];
    const int tid = threadIdx.x;

    for (int i = tid; i < Bq * Kn; i += RS_BLK) qlds[i] = qidx_ws[i];
    if (tid < 80) {
        const int c = tid;
        float sx0 = fmaf(0.4f, (float)(4 * c), -0.3f);
        int i0 = (int)floorf(sx0);
        int s0 = min(max(i0, 0), MWs - 4);
        s0lds[c] = s0;
        #pragma unroll
        for (int t = 0; t < 4; ++t) {
            int ox = 4 * c + t;
            float sx = fmaf(0.4f, (float)ox, -0.3f);
            int ix0 = (int)floorf(sx);
            float fr = sx - (float)ix0;
            int ca = max(ix0, 0);
            int cb = min(ix0 + 1, MWs - 1);
            float wa = 1.0f - fr, wb = fr;
            vf4 w;
            #pragma unroll
            for (int j = 0; j < 4; ++j) {
                float v = 0.0f;
                if (s0 + j == ca) v += wa;
                if (s0 + j == cb) v += wb;
                w[j] = v;
            }
            Wlds[t * 80 + c] = w;
        }
    }
    __syncthreads();

    const int g = blockIdx.x * RS_BLK + tid;
    vf4* out4 = (vf4*)(out + OFF_MASKS);

    #pragma unroll 1
    for (int it = 0; it < RS_ITERS; ++it) {
        const int f  = it * RS_THREADS + g;
        const int bk = f / 25600;
        const int p  = f - bk * 25600;
        const int oy = p / 80;
        const int og = p - oy * 80;

        const int m  = oy / 5;
        const int ph = oy - 5 * m;
        int rA = 2 * m + ((ph == 0) ? -1 : ((ph == 4) ? 1 : 0));
        int rB = min(rA + 1, MHs - 1);
        rA = max(rA, 0);
        const float wA = (ph == 0) ? 0.3f : (ph == 1) ? 0.9f :
                         (ph == 2) ? 0.5f : (ph == 3) ? 0.1f : 0.7f;
        const float wB = (ph == 0) ? 0.7f : (ph == 1) ? 0.1f :
                         (ph == 2) ? 0.5f : (ph == 3) ? 0.9f : 0.3f;

        const int qq = qlds[bk];
        const int bb = (bk >= Kn) ? 1 : 0;
        const float* M = masks + ((size_t)(bb * Qn + qq)) * (MHs * MWs);
        const int s0 = s0lds[og];

        uvf4 aA = *(const uvf4*)(M + rA * MWs + s0);
        uvf4 aB = *(const uvf4*)(M + rB * MWs + s0);

        vf4 o;
        #pragma unroll
        for (int t = 0; t < 4; ++t) {
            vf4 w = Wlds[t * 80 + og];
            float hA = fmaf(w[0], aA[0], fmaf(w[1], aA[1],
                       fmaf(w[2], aA[2], w[3] * aA[3])));
            float hB = fmaf(w[0], aB[0], fmaf(w[1], aB[1],
                       fmaf(w[2], aB[2], w[3] * aB[3])));
            float v  = fmaf(wA, hA, wB * hB);
            o[t] = (v > 0.0f) ? 1.0f : 0.0f;
        }
        out4[f] = o;
    }
}

// ---------------------------------------------------------------------------
extern "C" void kernel_launch(void* const* d_in, const int* in_sizes, int n_in,
                              void* d_out, int out_size, void* d_ws, size_t ws_size,
                              hipStream_t stream) {
    const float* logits = (const float*)d_in[0];   // [B,Q,C]
    const float* boxes  = (const float*)d_in[1];   // [B,Q,4]
    const float* masks  = (const float*)d_in[2];   // [B,Q,128,128]
    const float* osz    = (const float*)d_in[3];   // [B,2]

    float* out = (float*)d_out;
    char* ws = (char*)d_ws;
    int* ghist = (int*)(ws + WS_GHIST);
    int* cnt   = (int*)(ws + WS_CNT);
    int* thr   = (int*)(ws + WS_THR);
    unsigned long long* cand = (unsigned long long*)(ws + WS_CAND);
    int* qidx  = (int*)(ws + WS_QIDX);

    hipMemsetAsync(ws, 0, WS_ZERO_BYTES, stream);  // zero ghist+cnt

    dim3 g47(47, Bq);
    tk_hist<<<g47, 256, 0, stream>>>(logits, ghist);
    tk_thresh<<<Bq, 64, 0, stream>>>(ghist, thr);
    tk_collect<<<g47, 256, 0, stream>>>(logits, thr, cnt, cand);
    tk_rank<<<Bq, 1024, 0, stream>>>(cnt, cand, boxes, osz, out, qidx);

    // Measurement: 3x identical (idempotent) resize launches; dtotal = 2R.
    resize_sweep<<<RS_GRID, RS_BLK, 0, stream>>>(masks, qidx, out);
    resize_sweep<<<RS_GRID, RS_BLK, 0, stream>>>(masks, qidx, out);
    resize_sweep<<<RS_GRID, RS_BLK, 0, stream>>>(masks, qidx, out);
}

// Round 11
// 335.863 us; speedup vs baseline: 1.3746x; 1.3746x over previous
//
#include <hip/hip_runtime.h>
#include <stdint.h>

// Problem constants (static shapes from the reference)
constexpr int Bq = 2;
constexpr int Qn = 300;
constexpr int Cn = 80;
constexpr int Kn = 300;
constexpr int NFLAT = Qn * Cn;   // 24000
constexpr int MHs = 128;
constexpr int MWs = 128;
constexpr int THs = 320;
constexpr int TWs = 320;

// Output layout (flat concatenation in reference return order, all as float)
constexpr int OFF_SCORES = 0;                         // [B,K]     600
constexpr int OFF_LABELS = Bq * Kn;                   // [B,K]     600
constexpr int OFF_BOXES  = 2 * Bq * Kn;               // [B,K,4]   2400
constexpr int OFF_MASKS  = 2 * Bq * Kn + Bq * Kn * 4; // [B,K,320,320]

typedef float vf4  __attribute__((ext_vector_type(4)));              // 16B-aligned
typedef float uvf4 __attribute__((ext_vector_type(4), aligned(4)));  // align-4 load

constexpr int HB = 47;                // hist blocks per batch

// Workspace layout (bytes) — every slot fully overwritten each call
constexpr size_t WS_GHIST = 0;        // int[2][47][256] private slices (96 KB)
constexpr size_t WS_CNT   = 98304;    // int[2]
constexpr size_t WS_CAND  = 98432;    // u64[2*1024]
constexpr size_t WS_QIDX  = 114816;   // int[600]

// ---------------------------------------------------------------------------
// topk pass 1: per-block PRIVATE histogram slices (no global atomics, no
// memset). Round-10 measurement: resize=58us, topk chain+gaps=103us; the pig
// was tk_thresh's 256 loop-carried global loads on ONE thread (~80us of
// L2-miss round trips). Slices let pass 2 rebuild+scan the histogram with
// parallel loads instead. Block (0,0) also zeroes cnt (stream-ordered).
// ---------------------------------------------------------------------------
__global__ __launch_bounds__(256) void tk_hist(
    const float* __restrict__ logits, int* __restrict__ ghist,
    int* __restrict__ cnt)
{
    const int b = blockIdx.y;
    __shared__ int lh[256];
    lh[threadIdx.x] = 0;
    __syncthreads();
    const float* lg = logits + (size_t)b * NFLAT;
    #pragma unroll
    for (int j = 0; j < 2; ++j) {
        int idx = blockIdx.x * 512 + j * 256 + threadIdx.x;
        if (idx < NFLAT) {
            float x = lg[idx];
            int bin = min(max((int)floorf((x + 8.0f) * 16.0f), 0), 255);
            atomicAdd(&lh[bin], 1);
        }
    }
    __syncthreads();
    ghist[((b * HB) + blockIdx.x) * 256 + threadIdx.x] = lh[threadIdx.x];
    if (blockIdx.x == 0 && b == 0 && threadIdx.x < Bq) cnt[threadIdx.x] = 0;
}

// ---------------------------------------------------------------------------
// topk pass 2: each block independently rebuilds the per-batch histogram
// (256 threads x 47 coalesced slice loads), suffix-scans it in LDS (8 steps),
// finds the threshold bin, then collects candidates with an LDS-local buffer
// and ONE device atomicAdd per block. key=(sigmoid_bits<<32)|~idx (unique;
// exact jax.lax.top_k order incl. tie -> lowest flat index).
// ---------------------------------------------------------------------------
__global__ __launch_bounds__(256) void tk_collect(
    const float* __restrict__ logits, const int* __restrict__ ghist,
    int* __restrict__ cnt, unsigned long long* __restrict__ cand)
{
    const int b   = blockIdx.y;
    const int tid = threadIdx.x;

    __shared__ int sA[256], sB[256];
    __shared__ int s_T;
    __shared__ unsigned long long lbuf[512];
    __shared__ int lcnt, lbase;

    // Rebuild per-batch histogram: parallel coalesced loads (the anti-thresh)
    int s = 0;
    #pragma unroll
    for (int blk = 0; blk < HB; ++blk)
        s += ghist[((b * HB) + blk) * 256 + tid];
    sA[tid] = s;
    if (tid == 0) lcnt = 0;
    __syncthreads();

    // Suffix scan (count of elements with bin >= i)
    int* src = sA;
    int* dst = sB;
    for (int d = 1; d < 256; d <<= 1) {
        int v = src[tid] + ((tid + d < 256) ? src[tid + d] : 0);
        dst[tid] = v;
        __syncthreads();
        int* t = src; src = dst; dst = t;
    }
    int sfx  = src[tid];
    int sfx1 = (tid < 255) ? src[tid + 1] : 0;
    if (sfx >= Kn && sfx1 < Kn) s_T = tid;   // single crossing (sfx monotone)
    __syncthreads();
    const int T = s_T;

    // Collect candidates from this block's 512 elements
    const float* lg = logits + (size_t)b * NFLAT;
    #pragma unroll
    for (int j = 0; j < 2; ++j) {
        int idx = blockIdx.x * 512 + j * 256 + tid;
        if (idx < NFLAT) {
            float x = lg[idx];
            int bin = min(max((int)floorf((x + 8.0f) * 16.0f), 0), 255);
            if (bin >= T) {
                float sg = 1.0f / (1.0f + expf(-x));   // same formula rounds 1-10
                int p = atomicAdd(&lcnt, 1);
                if (p < 512)
                    lbuf[p] = ((unsigned long long)__float_as_uint(sg) << 32)
                            | (unsigned long long)(0xFFFFFFFFu - (uint32_t)idx);
            }
        }
    }
    __syncthreads();
    if (tid == 0) { lcnt = min(lcnt, 512); lbase = atomicAdd(&cnt[b], lcnt); }
    __syncthreads();
    for (int i = tid; i < lcnt; i += 256) {
        int d = lbase + i;
        if (d < 1024) cand[b * 1024 + d] = lbuf[i];
    }
}

// ---------------------------------------------------------------------------
// topk pass 3: rank candidates by count (unique keys => permutation), emit
// scores/labels/boxes/qidx for ranks < K.
// ---------------------------------------------------------------------------
__global__ __launch_bounds__(1024) void tk_rank(
    const int* __restrict__ cnt, const unsigned long long* __restrict__ cand,
    const float* __restrict__ boxes, const float* __restrict__ osz,
    float* __restrict__ out, int* __restrict__ qidx_ws)
{
    const int b   = blockIdx.x;
    const int tid = threadIdx.x;
    __shared__ unsigned long long sk[1024];
    const int n = min(cnt[b], 1024);
    sk[tid] = (tid < n) ? cand[b * 1024 + tid] : 0ull;
    __syncthreads();

    if (tid < n) {
        unsigned long long my = sk[tid];
        int rank = 0;
        for (int i = 0; i < n; ++i) rank += (sk[i] > my) ? 1 : 0;
        if (rank < Kn) {
            uint32_t idx = 0xFFFFFFFFu - (uint32_t)(my & 0xFFFFFFFFull);
            float score  = __uint_as_float((uint32_t)(my >> 32));
            int label = (int)(idx % (uint32_t)Cn);
            int q     = (int)(idx / (uint32_t)Cn);

            out[OFF_SCORES + b * Kn + rank] = score;
            out[OFF_LABELS + b * Kn + rank] = (float)label;

            const float sw = osz[b * 2 + 0];
            const float sh = osz[b * 2 + 1];
            const float* bx = boxes + ((size_t)(b * Qn + q)) * 4;
            float cx = bx[0], cy = bx[1], w = bx[2], h = bx[3];
            float* ob = out + OFF_BOXES + ((size_t)(b * Kn + rank)) * 4;
            ob[0] = (cx - 0.5f * w) * sw;
            ob[1] = (cy - 0.5f * h) * sh;
            ob[2] = (cx + 0.5f * w) * sw;
            ob[3] = (cy + 0.5f * h) * sh;

            qidx_ws[b * Kn + rank] = q;
        }
    }
}

// ---------------------------------------------------------------------------
// resize v8 (byte-identical to rounds 9/10; measured 58us, ~1.4x the 41us
// pure-write floor): grid-stride flat sweep, fill-style sequential writes.
// ---------------------------------------------------------------------------
constexpr int RS_GRID = 2400;
constexpr int RS_BLK  = 256;
constexpr int RS_THREADS = RS_GRID * RS_BLK;               // 614400
constexpr int N4 = Bq * Kn * (THs * TWs / 4);              // 15,360,000
constexpr int RS_ITERS = N4 / RS_THREADS;                  // 25 (exact)

__global__ __launch_bounds__(256) void resize_sweep(
    const float* __restrict__ masks,    // [B,Q,128,128]
    const int* __restrict__ qidx_ws,    // [B,K]
    float* __restrict__ out)
{
    __shared__ int  qlds[Bq * Kn];
    __shared__ int  s0lds[80];
    __shared__ vf4  Wlds[4 * 80];
    const int tid = threadIdx.x;

    for (int i = tid; i < Bq * Kn; i += RS_BLK) qlds[i] = qidx_ws[i];
    if (tid < 80) {
        const int c = tid;
        float sx0 = fmaf(0.4f, (float)(4 * c), -0.3f);
        int i0 = (int)floorf(sx0);
        int s0 = min(max(i0, 0), MWs - 4);
        s0lds[c] = s0;
        #pragma unroll
        for (int t = 0; t < 4; ++t) {
            int ox = 4 * c + t;
            float sx = fmaf(0.4f, (float)ox, -0.3f);
            int ix0 = (int)floorf(sx);
            float fr = sx - (float)ix0;
            int ca = max(ix0, 0);
            int cb = min(ix0 + 1, MWs - 1);
            float wa = 1.0f - fr, wb = fr;
            vf4 w;
            #pragma unroll
            for (int j = 0; j < 4; ++j) {
                float v = 0.0f;
                if (s0 + j == ca) v += wa;
                if (s0 + j == cb) v += wb;
                w[j] = v;
            }
            Wlds[t * 80 + c] = w;
        }
    }
    __syncthreads();

    const int g = blockIdx.x * RS_BLK + tid;
    vf4* out4 = (vf4*)(out + OFF_MASKS);

    #pragma unroll 1
    for (int it = 0; it < RS_ITERS; ++it) {
        const int f  = it * RS_THREADS + g;
        const int bk = f / 25600;
        const int p  = f - bk * 25600;
        const int oy = p / 80;
        const int og = p - oy * 80;

        const int m  = oy / 5;
        const int ph = oy - 5 * m;
        int rA = 2 * m + ((ph == 0) ? -1 : ((ph == 4) ? 1 : 0));
        int rB = min(rA + 1, MHs - 1);
        rA = max(rA, 0);
        const float wA = (ph == 0) ? 0.3f : (ph == 1) ? 0.9f :
                         (ph == 2) ? 0.5f : (ph == 3) ? 0.1f : 0.7f;
        const float wB = (ph == 0) ? 0.7f : (ph == 1) ? 0.1f :
                         (ph == 2) ? 0.5f : (ph == 3) ? 0.9f : 0.3f;

        const int qq = qlds[bk];
        const int bb = (bk >= Kn) ? 1 : 0;
        const float* M = masks + ((size_t)(bb * Qn + qq)) * (MHs * MWs);
        const int s0 = s0lds[og];

        uvf4 aA = *(const uvf4*)(M + rA * MWs + s0);
        uvf4 aB = *(const uvf4*)(M + rB * MWs + s0);

        vf4 o;
        #pragma unroll
        for (int t = 0; t < 4; ++t) {
            vf4 w = Wlds[t * 80 + og];
            float hA = fmaf(w[0], aA[0], fmaf(w[1], aA[1],
                       fmaf(w[2], aA[2], w[3] * aA[3])));
            float hB = fmaf(w[0], aB[0], fmaf(w[1], aB[1],
                       fmaf(w[2], aB[2], w[3] * aB[3])));
            float v  = fmaf(wA, hA, wB * hB);
            o[t] = (v > 0.0f) ? 1.0f : 0.0f;
        }
        out4[f] = o;
    }
}

// ---------------------------------------------------------------------------
extern "C" void kernel_launch(void* const* d_in, const int* in_sizes, int n_in,
                              void* d_out, int out_size, void* d_ws, size_t ws_size,
                              hipStream_t stream) {
    const float* logits = (const float*)d_in[0];   // [B,Q,C]
    const float* boxes  = (const float*)d_in[1];   // [B,Q,4]
    const float* masks  = (const float*)d_in[2];   // [B,Q,128,128]
    const float* osz    = (const float*)d_in[3];   // [B,2]

    float* out = (float*)d_out;
    char* ws = (char*)d_ws;
    int* ghist = (int*)(ws + WS_GHIST);
    int* cnt   = (int*)(ws + WS_CNT);
    unsigned long long* cand = (unsigned long long*)(ws + WS_CAND);
    int* qidx  = (int*)(ws + WS_QIDX);

    dim3 gh(HB, Bq);
    tk_hist<<<gh, 256, 0, stream>>>(logits, ghist, cnt);
    tk_collect<<<gh, 256, 0, stream>>>(logits, ghist, cnt, cand);
    tk_rank<<<Bq, 1024, 0, stream>>>(cnt, cand, boxes, osz, out, qidx);
    resize_sweep<<<RS_GRID, RS_BLK, 0, stream>>>(masks, qidx, out);
}